// Round 3
// baseline (38115.558 us; speedup 1.0000x reference)
//
#include <hip/hip_runtime.h>
#include <hip/hip_bf16.h>
#include <math.h>
#include <stdio.h>

// EncoDecLSTM: B=256, T=512, F=128, U=1024.
// R3: fp32-equivalent recurrence via 3-limb bf16 MFMA (hi/mid/lo = 24 mantissa
// bits; 6 limb products hh,hm,mh,mm,hl,lh with fp32 accumulate). The decoder
// Jacobian has modes with |lambda|~1.06 -> plain bf16 h-feedback noise (4e-4)
// saturates to O(1) after 512 steps (R2: absmax 1.06). fp32-grade noise
// (~1e-7) stays ~1e-3 under the same amplification.
// Decoder identity: x_in == h, so z = h@(dec_Wx+dec_Wh)+b.
// Encoder folds x@Wx via K-concat (K=1152=36*32).

typedef __attribute__((ext_vector_type(8))) short short8;   // 8 x bf16
typedef __attribute__((ext_vector_type(4))) float f32x4;

#define MFMA(a, b, c) __builtin_amdgcn_mfma_f32_16x16x32_bf16(a, b, c, 0, 0, 0)

__device__ __forceinline__ short f2bf(float f) {
  union { __hip_bfloat16 h; short s; } u;
  u.h = __float2bfloat16(f);
  return u.s;
}
__device__ __forceinline__ void split3(float x, short& a, short& b, short& c) {
  union { __hip_bfloat16 h; short s; } u;
  u.h = __float2bfloat16(x); a = u.s;
  float r1 = x - __bfloat162float(u.h);
  u.h = __float2bfloat16(r1); b = u.s;
  float r2 = r1 - __bfloat162float(u.h);
  u.h = __float2bfloat16(r2); c = u.s;
}
__device__ __forceinline__ float sigm(float x) { return 1.0f / (1.0f + expf(-x)); }

// ---------------------------------------------------------------------------
// Pack weight matrix into B-fragment layout, 1 or 3 limbs.
// limbs==3: dst[((nt*KC+kc)*3+l)*64+lane][j] ; limbs==1: dst[(nt*KC+kc)*64+lane][j]
// holds B[k = kc*32 + (lane>>4)*8 + j][col]
// mode 0: dec combined (a+b), gate-grouped cols. mode 1: enc concat (k<1024 ->
// a=Wh else b=Wx[k-1024]), gate-grouped. mode 2/3: natural cols (ncols).
// gate-grouped: nt = ub*4+g -> col = g*1024 + ub*16 + (lane&15)
// ---------------------------------------------------------------------------
__global__ void pack_w(const float* __restrict__ a, const float* __restrict__ b,
                       short8* __restrict__ dst, int KC, int mode, int ncols,
                       int limbs) {
  int gid = blockIdx.x * 256 + threadIdx.x;
  int lane = gid & 63;
  int kc = (gid >> 6) % KC;
  int nt = gid / (KC * 64);
  int u16 = lane & 15, kq = lane >> 4;
  int kbase = kc * 32 + kq * 8;
  int col;
  if (mode <= 1) { int g = nt & 3, ub = nt >> 2; col = g * 1024 + ub * 16 + u16; }
  else col = nt * 16 + u16;
  short8 v0, v1, v2;
#pragma unroll
  for (int j = 0; j < 8; ++j) {
    int k = kbase + j;
    float x;
    if (mode == 0)      x = a[(size_t)k * 4096 + col] + b[(size_t)k * 4096 + col];
    else if (mode == 1) x = (k < 1024) ? a[(size_t)k * 4096 + col]
                                       : b[(size_t)(k - 1024) * 4096 + col];
    else                x = a[(size_t)k * ncols + col];
    short sa, sb, sc; split3(x, sa, sb, sc);
    v0[j] = sa; v1[j] = sb; v2[j] = sc;
  }
  if (limbs == 3) {
    size_t base = (size_t)(nt * KC + kc) * 3 * 64 + lane;
    dst[base] = v0; dst[base + 64] = v1; dst[base + 128] = v2;
  } else {
    dst[(size_t)(nt * KC + kc) * 64 + lane] = v0;
  }
}

// Pack 32 timesteps of input x into 3-limb A-fragment ring.
// dst[(((tloc*16+mt)*4+kx)*3+l)*64+lane][j] = x[b=mt*16+(lane&15)][t0+tloc][f=kx*32+(lane>>4)*8+j]
__global__ void pack_x32(const float* __restrict__ src, short8* __restrict__ dst,
                         int t0) {
  int gid = blockIdx.x * 256 + threadIdx.x;
  int lane = gid & 63;
  int kx = (gid >> 6) & 3;
  int mt = (gid >> 8) & 15;
  int tloc = gid >> 12;            // 0..31
  int bb = mt * 16 + (lane & 15);
  int fb = kx * 32 + (lane >> 4) * 8;
  const float* s = src + ((size_t)bb * 512 + (t0 + tloc)) * 128 + fb;
  short8 v0, v1, v2;
#pragma unroll
  for (int j = 0; j < 8; ++j) {
    short sa, sb, sc; split3(s[j], sa, sb, sc);
    v0[j] = sa; v1[j] = sb; v2[j] = sc;
  }
  size_t base = (size_t)((tloc * 16 + mt) * 4 + kx) * 3 * 64 + lane;
  dst[base] = v0; dst[base + 64] = v1; dst[base + 128] = v2;
}

__global__ void zero_f(float* p, int n) {
  int i = blockIdx.x * 256 + threadIdx.x;
  if (i < n) p[i] = 0.f;
}

// ---------------------------------------------------------------------------
// One LSTM timestep, 3-limb GEMM + fp32 gates. 256 blocks x 512 thr.
// Block owns 64 rows (mb) x 16 units (ub) -> 64 gate-cols. 8 waves:
// wr = wv&3 (one 16-row tile), wc = wv>>2 (two gate-col tiles).
// Per kc: 3 A-limb + 6 B-limb loads, 12 MFMA (2 tiles x 6 limb products).
// A-fragment (3-limb): idx ((mt*32+kc)*3+l)*64+lane ; x-part via Ax (KC=36).
// ---------------------------------------------------------------------------
__global__ __launch_bounds__(512) void lstm_step(
    const short8* __restrict__ Ah, const short8* __restrict__ Ax,
    const short8* __restrict__ W, const float* __restrict__ bias,
    float* __restrict__ cst, short8* __restrict__ Hnext,
    short8* __restrict__ Hring, int KC) {
  int tid = threadIdx.x;
  int lane = tid & 63, wv = tid >> 6;
  int wr = wv & 3, wc = wv >> 2;
  int xcd = blockIdx.x & 7, idx = blockIdx.x >> 3;
  int mb = idx & 3, ub = xcd * 8 + (idx >> 2);   // ub in [0,64)
  int mt = mb * 4 + wr;                          // 16-row tile of A
  int nt0 = ub * 4 + wc * 2, nt1 = nt0 + 1;      // gate-col tiles
  const f32x4 z4 = {0.f, 0.f, 0.f, 0.f};
  f32x4 acc0 = z4, acc1 = z4;
  for (int kc = 0; kc < KC; ++kc) {
    const short8* Ap = (kc < 32)
        ? (Ah + ((size_t)(mt * 32 + kc) * 3) * 64 + lane)
        : (Ax + ((size_t)(mt * 4 + (kc - 32)) * 3) * 64 + lane);
    short8 a0 = Ap[0], a1 = Ap[64], a2 = Ap[128];
    const short8* Bp = W + ((size_t)(nt0 * KC + kc) * 3) * 64 + lane;
    const short8* Bq = W + ((size_t)(nt1 * KC + kc) * 3) * 64 + lane;
    short8 b00 = Bp[0], b01 = Bp[64], b02 = Bp[128];
    short8 b10 = Bq[0], b11 = Bq[64], b12 = Bq[128];
    // limb products: hh, hm, mh, mm, hl, lh  (residual ~2^-24)
    acc0 = MFMA(a0, b00, acc0);  acc1 = MFMA(a0, b10, acc1);
    acc0 = MFMA(a0, b01, acc0);  acc1 = MFMA(a0, b11, acc1);
    acc0 = MFMA(a1, b00, acc0);  acc1 = MFMA(a1, b10, acc1);
    acc0 = MFMA(a1, b01, acc0);  acc1 = MFMA(a1, b11, acc1);
    acc0 = MFMA(a0, b02, acc0);  acc1 = MFMA(a0, b12, acc1);
    acc0 = MFMA(a2, b00, acc0);  acc1 = MFMA(a2, b10, acc1);
  }

  __shared__ float zt[64][68];   // [row][gate*16 + u], pad to 68
  int u16 = lane & 15, quad = lane >> 4;
  float bv0 = bias[(wc * 2 + 0) * 1024 + ub * 16 + u16];
  float bv1 = bias[(wc * 2 + 1) * 1024 + ub * 16 + u16];
  // C/D layout: col = lane&15, row = quad*4 + reg   (m89/m91-verified)
#pragma unroll
  for (int r = 0; r < 4; ++r) {
    zt[wr * 16 + quad * 4 + r][(wc * 2 + 0) * 16 + u16] = acc0[r] + bv0;
    zt[wr * 16 + quad * 4 + r][(wc * 2 + 1) * 16 + u16] = acc1[r] + bv1;
  }
  __syncthreads();

  if (tid < 128) {
    int r = tid >> 1, s = tid & 1;     // row 0..63, u-octet 0..1
    int m = mb * 64 + r;
    int ubase = ub * 16 + s * 8;
    float* cp = cst + (size_t)m * 1024 + ubase;
    short8 h0, h1, h2;
#pragma unroll
    for (int j = 0; j < 8; ++j) {
      int uu = s * 8 + j;
      float iv = zt[r][uu];
      float fv = zt[r][16 + uu];
      float gv = zt[r][32 + uu];
      float ov = zt[r][48 + uu];
      float cn = sigm(fv) * cp[j] + sigm(iv) * tanhf(gv);
      cp[j] = cn;
      float hval = sigm(ov) * tanhf(cn);
      short sa, sb, sc; split3(hval, sa, sb, sc);
      h0[j] = sa; h1[j] = sb; h2[j] = sc;
    }
    // emit h in 3-limb A-fragment layout for the next step's GEMM
    int mtw = m >> 4, r16 = m & 15;
    int kcw = ubase >> 5, ko = ubase & 31;
    int lane_t = r16 + 16 * (ko >> 3);
    size_t base = ((size_t)(mtw * 32 + kcw) * 3) * 64 + lane_t;
    Hnext[base] = h0; Hnext[base + 64] = h1; Hnext[base + 128] = h2;
    if (Hring)  // hi limb only, single-limb layout, for the projection
      Hring[(size_t)(mtw * 32 + kcw) * 64 + lane_t] = h0;
  }
}

// ---------------------------------------------------------------------------
// Fused projection: y = relu(hs @ d1W + b1) @ d2W + b2 over a 32-step chunk.
// 128 blocks x 256 thr; hs = hi-limb ring (single pass, bf16 error ~1e-3 ok).
// ---------------------------------------------------------------------------
__global__ __launch_bounds__(256) void proj(
    const short8* __restrict__ HS, const short8* __restrict__ W1,
    const float* __restrict__ b1, const short8* __restrict__ W2,
    const float* __restrict__ b2, float* __restrict__ out, int t0) {
  int tid = threadIdx.x;
  int lane = tid & 63, wv = tid >> 6;
  int wr = wv & 1, wc = wv >> 1;
  int tloc = blockIdx.x >> 2, mb = blockIdx.x & 3;
  int t = t0 + tloc;
  const short8* A = HS + (size_t)tloc * 16 * 32 * 64;
  int u16 = lane & 15, quad = lane >> 4;
  int mt0 = mb * 4 + wr * 2;
  __shared__ short a1f[4][8][512];   // A1 quarter in A-fragment layout, 32 KB
  const f32x4 z4 = {0.f, 0.f, 0.f, 0.f};
  f32x4 acc2[2][4];
#pragma unroll
  for (int i = 0; i < 2; ++i)
#pragma unroll
    for (int jj = 0; jj < 4; ++jj) acc2[i][jj] = z4;

  for (int q = 0; q < 4; ++q) {
    f32x4 acc1[2][8];
#pragma unroll
    for (int i = 0; i < 2; ++i)
#pragma unroll
      for (int n = 0; n < 8; ++n) acc1[i][n] = z4;
    for (int kc = 0; kc < 32; ++kc) {
      short8 av0 = A[(size_t)(mt0 * 32 + kc) * 64 + lane];
      short8 av1 = A[(size_t)((mt0 + 1) * 32 + kc) * 64 + lane];
#pragma unroll
      for (int n = 0; n < 8; ++n) {
        int nt = q * 16 + wc * 8 + n;
        short8 bv = W1[(size_t)(nt * 32 + kc) * 64 + lane];
        acc1[0][n] = MFMA(av0, bv, acc1[0][n]);
        acc1[1][n] = MFMA(av1, bv, acc1[1][n]);
      }
    }
    __syncthreads();   // previous quarter's GEMM2 reads are done
#pragma unroll
    for (int i = 0; i < 2; ++i)
#pragma unroll
      for (int n = 0; n < 8; ++n)
#pragma unroll
        for (int r = 0; r < 4; ++r) {
          int rl = wr * 32 + i * 16 + quad * 4 + r;
          int nloc = wc * 128 + n * 16 + u16;
          float v = fmaxf(acc1[i][n][r] + b1[q * 256 + nloc], 0.f);
          int mtl = rl >> 4, r16 = rl & 15;
          int kcl = nloc >> 5, ko = nloc & 31;
          a1f[mtl][kcl][(r16 + 16 * (ko >> 3)) * 8 + (ko & 7)] = f2bf(v);
        }
    __syncthreads();
    for (int kcl = 0; kcl < 8; ++kcl) {
      short8 av0 = *(const short8*)&a1f[wr * 2 + 0][kcl][lane * 8];
      short8 av1 = *(const short8*)&a1f[wr * 2 + 1][kcl][lane * 8];
#pragma unroll
      for (int jj = 0; jj < 4; ++jj) {
        int nt2 = wc * 4 + jj;
        short8 bv = W2[(size_t)(nt2 * 32 + q * 8 + kcl) * 64 + lane];
        acc2[0][jj] = MFMA(av0, bv, acc2[0][jj]);
        acc2[1][jj] = MFMA(av1, bv, acc2[1][jj]);
      }
    }
  }
#pragma unroll
  for (int i = 0; i < 2; ++i)
#pragma unroll
    for (int jj = 0; jj < 4; ++jj)
#pragma unroll
      for (int r = 0; r < 4; ++r) {
        int rl = wr * 32 + i * 16 + quad * 4 + r;
        int f = wc * 64 + jj * 16 + u16;
        int bb = mb * 64 + rl;
        out[((size_t)bb * 512 + t) * 128 + f] = acc2[i][jj][r] + b2[f];
      }
}

extern "C" void kernel_launch(void* const* d_in, const int* in_sizes, int n_in,
                              void* d_out, int out_size, void* d_ws, size_t ws_size,
                              hipStream_t stream) {
  const float* x     = (const float*)d_in[0];
  const float* encWx = (const float*)d_in[1];
  const float* encWh = (const float*)d_in[2];
  const float* encb  = (const float*)d_in[3];
  const float* decWx = (const float*)d_in[4];
  const float* decWh = (const float*)d_in[5];
  const float* decb  = (const float*)d_in[6];
  const float* d1W   = (const float*)d_in[7];
  const float* d1b   = (const float*)d_in[8];
  const float* d2W   = (const float*)d_in[9];
  const float* d2b   = (const float*)d_in[10];

  char* ws = (char*)d_ws;
  size_t off = 0;
  short8* Wenc = (short8*)(ws + off); off += (size_t)256 * 36 * 3 * 64 * 16;  // 28.3 MB
  short8* Wdec = (short8*)(ws + off); off += (size_t)256 * 32 * 3 * 64 * 16;  // 25.2 MB
  short8* W1   = (short8*)(ws + off); off += (size_t)64 * 32 * 64 * 16;       //  2.10 MB
  short8* W2   = (short8*)(ws + off); off += (size_t)8 * 32 * 64 * 16;        //  0.26 MB
  short8* Xr   = (short8*)(ws + off); off += (size_t)32 * 16 * 4 * 3 * 64 * 16;   //  6.29 MB
  short8* Hb   = (short8*)(ws + off); off += (size_t)2 * 16 * 32 * 3 * 64 * 16;   //  3.15 MB
  short8* Hring= (short8*)(ws + off); off += (size_t)32 * 16 * 32 * 64 * 16;      // 16.78 MB
  float*  cst  = (float*)(ws + off);  off += (size_t)256 * 1024 * 4;              //  1.05 MB
  (void)in_sizes; (void)n_in; (void)out_size;  // total ~83.1 MB
  if (ws_size < off) {
    fprintf(stderr, "kernel_launch: ws_size=%zu < needed=%zu -- aborting launch\n",
            ws_size, off);
    return;
  }

  pack_w<<<2304, 256, 0, stream>>>(encWh, encWx, Wenc, 36, 1, 4096, 3);
  pack_w<<<2048, 256, 0, stream>>>(decWx, decWh, Wdec, 32, 0, 4096, 3);
  pack_w<<<512, 256, 0, stream>>>(d1W, nullptr, W1, 32, 2, 1024, 1);
  pack_w<<<64, 256, 0, stream>>>(d2W, nullptr, W2, 32, 3, 128, 1);
  zero_f<<<1536, 256, 0, stream>>>((float*)Hb, 16 * 32 * 3 * 64 * 8);  // h0 = 0 (buf 0)
  zero_f<<<1024, 256, 0, stream>>>(cst, 256 * 1024);                   // c0 = 0

  const size_t H3 = (size_t)16 * 32 * 3 * 64;   // short8 per 3-limb h-state
  const size_t XT = (size_t)16 * 4 * 3 * 64;    // short8 per 3-limb x step
  const size_t HR = (size_t)16 * 32 * 64;       // short8 per hi-limb h-state

  for (int c = 0; c < 16; ++c) {                // encoder, 16 chunks x 32 steps
    pack_x32<<<512, 256, 0, stream>>>(x, Xr, c * 32);
    for (int i = 0; i < 32; ++i) {
      int t = c * 32 + i;
      lstm_step<<<256, 512, 0, stream>>>(Hb + (size_t)(t & 1) * H3, Xr + (size_t)i * XT,
                                         Wenc, encb, cst,
                                         Hb + (size_t)((t + 1) & 1) * H3, nullptr, 36);
    }
  }
  // final encoder h sits in Hb buffer 0 (parity of t=512)
  for (int c = 0; c < 16; ++c) {                // decoder, 16 chunks x 32 steps
    for (int i = 0; i < 32; ++i) {
      int d = c * 32 + i;
      lstm_step<<<256, 512, 0, stream>>>(Hb + (size_t)(d & 1) * H3, nullptr,
                                         Wdec, decb, cst,
                                         Hb + (size_t)((d + 1) & 1) * H3,
                                         Hring + (size_t)i * HR, 32);
    }
    proj<<<128, 256, 0, stream>>>(Hring, W1, d1b, W2, d2b, (float*)d_out, c * 32);
  }
}